// Round 5
// baseline (352.593 us; speedup 1.0000x reference)
//
#include <hip/hip_runtime.h>
#include <math.h>

// B=2, S=2048, H=2048, NH=16, KVH=4, D=128, layer 5.
// GEMMs on mfma_f32_16x16x32_bf16; attention on mfma_f32_32x32x16_bf16.
// valid logit = qk/sqrt(128); masked = huge-negative (exp -> 0, matches ref).
// Attention softmax runs in log2 domain: logits scaled by log2e/sqrt(128).

#define RSQ128 0.08838834764831845
#define LOG2E  1.4426950408889634
#define RS2L   ((float)(RSQ128 * LOG2E))
#define MASK2  (-567000.0f)   /* MASK_VALUE*6*log2e, finite, exp2 -> 0 */

typedef __attribute__((ext_vector_type(8))) short short8;    // 8 bf16 = 4 VGPR
typedef __attribute__((ext_vector_type(4))) float f32x4;     // 16x16 C/D
typedef __attribute__((ext_vector_type(16))) float f32x16;   // 32x32 C/D

static __device__ __forceinline__ unsigned short f2bf(float x) {
    union { float f; unsigned u; } v; v.f = x;
    unsigned r = v.u + 0x7FFFu + ((v.u >> 16) & 1u);   // RNE
    return (unsigned short)(r >> 16);
}

static __device__ __forceinline__ unsigned pack_bf16(float lo, float hi) {
#if __has_builtin(__builtin_amdgcn_cvt_pk_bf16_f32)
    return __builtin_bit_cast(unsigned, __builtin_amdgcn_cvt_pk_bf16_f32(lo, hi));
#else
    return (unsigned)f2bf(lo) | ((unsigned)f2bf(hi) << 16);
#endif
}

static __device__ __forceinline__ float fexp2(float x) {
#if __has_builtin(__builtin_amdgcn_exp2f)
    return __builtin_amdgcn_exp2f(x);
#else
    return exp2f(x);
#endif
}

static __device__ __forceinline__ void gl_lds16(const void* g, void* l) {
    __builtin_amdgcn_global_load_lds(
        (const __attribute__((address_space(1))) void*)g,
        (__attribute__((address_space(3))) void*)l, 16, 0, 0);
}

// ---------------------------------------------------------------------------
// fp32 -> bf16 convert, 8 elems/thread
// ---------------------------------------------------------------------------
__global__ void cvt_bf16(const float* __restrict__ in, unsigned short* __restrict__ out) {
    const int i = (blockIdx.x * 256 + threadIdx.x) * 8;
    const float4 a = *(const float4*)(in + i);
    const float4 b = *(const float4*)(in + i + 4);
    short8 o;
    o[0] = (short)f2bf(a.x); o[1] = (short)f2bf(a.y);
    o[2] = (short)f2bf(a.z); o[3] = (short)f2bf(a.w);
    o[4] = (short)f2bf(b.x); o[5] = (short)f2bf(b.y);
    o[6] = (short)f2bf(b.z); o[7] = (short)f2bf(b.w);
    *(short8*)(out + i) = o;
}

// ---------------------------------------------------------------------------
// V [8][2048][128] fp32 -> Vt [8][128][2048] bf16 (per (b,kvh) transpose)
// ---------------------------------------------------------------------------
__global__ void vtrans_bf16(const float* __restrict__ V, unsigned short* __restrict__ Vt) {
    __shared__ float Ts[64][65];
    const int t = threadIdx.x;
    const int s0 = blockIdx.x * 64, d0 = blockIdx.y * 64;
    const float* src = V + (size_t)blockIdx.z * 2048 * 128;
    unsigned short* dst = Vt + (size_t)blockIdx.z * 128 * 2048;
#pragma unroll
    for (int p = 0; p < 4; ++p) {
        const int f = p * 256 + t, r = f >> 4, cq = f & 15;
        const float4 v = *(const float4*)(src + (size_t)(s0 + r) * 128 + d0 + cq * 4);
        Ts[r][cq * 4 + 0] = v.x; Ts[r][cq * 4 + 1] = v.y;
        Ts[r][cq * 4 + 2] = v.z; Ts[r][cq * 4 + 3] = v.w;
    }
    __syncthreads();
#pragma unroll
    for (int p = 0; p < 2; ++p) {
        const int f = p * 256 + t, dr = f >> 3, c = f & 7;
        short8 o;
#pragma unroll
        for (int j = 0; j < 8; ++j) o[j] = (short)f2bf(Ts[c * 8 + j][dr]);
        *(short8*)(dst + (size_t)(d0 + dr) * 2048 + s0 + c * 8) = o;
    }
}

// ---------------------------------------------------------------------------
// NT GEMM bf16 MFMA (unchanged — known good)
// ---------------------------------------------------------------------------
template <bool BF16OUT>
__global__ __launch_bounds__(256, 2) void gemm_nt_mfma(
    const unsigned short* __restrict__ A,
    const unsigned short* __restrict__ W,
    const float* __restrict__ bias,
    void* __restrict__ Cout, int M, int N, int K)
{
    __shared__ __align__(16) unsigned short As[128 * 32];
    __shared__ __align__(16) unsigned short Ws[128 * 32];
    const int tid = threadIdx.x, lane = tid & 63, w = tid >> 6;
    const int wm = w & 1, wn = w >> 1;
    const int m0 = blockIdx.y * 128, n0 = blockIdx.x * 128;
    const int r0 = tid >> 2, c0 = tid & 3;

    const unsigned short* Ag = A + (size_t)(m0 + r0) * K + c0 * 8;
    const unsigned short* Wg = W + (size_t)(n0 + r0) * K + c0 * 8;

    f32x4 acc[4][4];
#pragma unroll
    for (int i = 0; i < 4; ++i)
#pragma unroll
        for (int j = 0; j < 4; ++j) acc[i][j] = (f32x4){0.f, 0.f, 0.f, 0.f};

    const int lm = lane & 15, lk = (lane >> 4) * 8;

    for (int k0 = 0; k0 < K; k0 += 32) {
        __syncthreads();
        gl_lds16(Ag + k0,                  As + tid * 8);
        gl_lds16(Ag + (size_t)64 * K + k0, As + (tid + 256) * 8);
        gl_lds16(Wg + k0,                  Ws + tid * 8);
        gl_lds16(Wg + (size_t)64 * K + k0, Ws + (tid + 256) * 8);
        __syncthreads();

        short8 a[4], b[4];
#pragma unroll
        for (int i = 0; i < 4; ++i)
            a[i] = *(const short8*)&As[(64 * wm + 16 * i + lm) * 32 + lk];
#pragma unroll
        for (int j = 0; j < 4; ++j)
            b[j] = *(const short8*)&Ws[(64 * wn + 16 * j + lm) * 32 + lk];
#pragma unroll
        for (int i = 0; i < 4; ++i)
#pragma unroll
            for (int j = 0; j < 4; ++j)
                acc[i][j] = __builtin_amdgcn_mfma_f32_16x16x32_bf16(a[i], b[j], acc[i][j], 0, 0, 0);
    }

    float bv[4];
#pragma unroll
    for (int j = 0; j < 4; ++j) bv[j] = bias[n0 + 64 * wn + 16 * j + lm];
#pragma unroll
    for (int i = 0; i < 4; ++i)
#pragma unroll
        for (int reg = 0; reg < 4; ++reg) {
            const int row = m0 + 64 * wm + 16 * i + 4 * (lane >> 4) + reg;
#pragma unroll
            for (int j = 0; j < 4; ++j) {
                const int col = n0 + 64 * wn + 16 * j + lm;
                const float v = acc[i][j][reg] + bv[j];
                if (BF16OUT) ((unsigned short*)Cout)[(size_t)row * N + col] = f2bf(v);
                else         ((float*)Cout)[(size_t)row * N + col] = v;
            }
        }
}

// ---------------------------------------------------------------------------
// Flash attention v4: DMA-staged chunk-major LDS tiles, log2-domain softmax.
// Br=64 (2 waves x 32 q), Bc=64, grid 1024 blocks, 32KB LDS.
//   Ks2[ch 0..15][key 0..63][8]  : K tile, chunk-major -> linear frag reads
//   Vs2[kc 0..7][d 0..127][8]    : Vt tile, chunk-major
// wave0 DMA-stages K (16 x global_load_lds dwordx4), wave1 stages V.
// St = K*Q^T (A from LDS, B=Q hoisted); Ot = V*P^T (P via 2 shfl/kstep).
// ---------------------------------------------------------------------------
__global__ __launch_bounds__(128, 4) void attn_mfma4(
    const unsigned short* __restrict__ Q,   // [4096][2048] bf16
    const unsigned short* __restrict__ Kg_, // [2,4,2048,128] bf16
    const unsigned short* __restrict__ Vt,  // [2,4,128,2048] bf16
    unsigned short* __restrict__ O)         // [4096][2048] bf16
{
    __shared__ __align__(16) unsigned short Ks2[16 * 64 * 8];   // 16KB
    __shared__ __align__(16) unsigned short Vs2[8 * 128 * 8];   // 16KB

    const int tid = threadIdx.x, lane = tid & 63, w = tid >> 6;  // w in {0,1}
    const int h2 = lane >> 5;
    const int ln = lane & 31;

    // qb permutation: stride-256 block sets have ~constant total work
    const int bid = blockIdx.x;
    const int jj = bid >> 5;                 // 0..31
    const int aa = jj & 7, bb = jj >> 3;
    const int qb = 8 * bb + ((bb & 1) ? (7 - aa) : aa);
    const int bh = bid & 31;
    const int s0 = qb * 64;
    const int b = bh >> 4, h = bh & 15, kh = h >> 2;

    const unsigned short* Kb = Kg_ + (size_t)(b * 4 + kh) * 2048 * 128;
    const unsigned short* Vg = Vt + (size_t)(b * 4 + kh) * 128 * 2048;

    // DMA source pointers (advance per key-tile)
    const unsigned short* kdma = Kb + (size_t)lane * 128;    // key = lane
    const unsigned short* vdma = Vg + (size_t)lane * 2048;   // d = lane (+64)

    // ---- hoist Q fragments: B[n=q=ln][k=16ks+8h2+j] ----
    const int qg = s0 + 32 * w + ln;
    const unsigned short* Qp = Q + (size_t)(b * 2048 + qg) * 2048 + h * 128 + h2 * 8;
    short8 Qreg[8];
#pragma unroll
    for (int ks = 0; ks < 8; ++ks) Qreg[ks] = *(const short8*)(Qp + ks * 16);

    f32x16 Ot[4];
#pragma unroll
    for (int mt = 0; mt < 4; ++mt)
#pragma unroll
        for (int r = 0; r < 16; ++r) Ot[mt][r] = 0.f;
    float m_ = -INFINITY, l_ = 0.f;

    // lane-constant LDS fragment bases
    const unsigned short* KsA = Ks2 + h2 * 512 + ln * 8;   // + ks*1024 + kt*256
    const unsigned short* VsA = Vs2 + h2 * 1024 + ln * 8;  // + ks4*2048 + mt*256

    for (int t0 = 0; t0 <= s0; t0 += 64) {
        __syncthreads();   // prev iter LDS reads done
        if (w == 0) {
#pragma unroll
            for (int ch = 0; ch < 16; ++ch)
                gl_lds16(kdma + ch * 8, Ks2 + ch * 512);
        } else {
#pragma unroll
            for (int kc = 0; kc < 8; ++kc) {
                gl_lds16(vdma + kc * 8,                     Vs2 + kc * 1024);
                gl_lds16(vdma + (size_t)64 * 2048 + kc * 8, Vs2 + kc * 1024 + 512);
            }
        }
        __syncthreads();   // barrier drains vmcnt -> DMA visible

        // ---- St = K Q^T : col=q=ln, rows=key ----
        f32x16 St[2];
#pragma unroll
        for (int kt = 0; kt < 2; ++kt)
#pragma unroll
            for (int r = 0; r < 16; ++r) St[kt][r] = 0.f;
#pragma unroll
        for (int ks = 0; ks < 8; ++ks)
#pragma unroll
            for (int kt = 0; kt < 2; ++kt) {
                const short8 a = *(const short8*)(KsA + ks * 1024 + kt * 256);
                St[kt] = __builtin_amdgcn_mfma_f32_32x32x16_bf16(a, Qreg[ks], St[kt], 0, 0, 0);
            }

        // ---- mask + scale to log2 domain; row max ----
        float mx = -INFINITY;
        if (t0 + 63 <= s0 + 32 * w) {     // wave fully unmasked
#pragma unroll
            for (int kt = 0; kt < 2; ++kt)
#pragma unroll
                for (int r = 0; r < 16; ++r) {
                    const float v = St[kt][r] * RS2L;
                    St[kt][r] = v;
                    mx = fmaxf(mx, v);
                }
        } else {
#pragma unroll
            for (int kt = 0; kt < 2; ++kt)
#pragma unroll
                for (int r = 0; r < 16; ++r) {
                    const int key = t0 + 32 * kt + (r & 3) + 8 * (r >> 2) + 4 * h2;
                    const float v = (key <= qg) ? St[kt][r] * RS2L : MASK2;
                    St[kt][r] = v;
                    mx = fmaxf(mx, v);
                }
        }
        mx = fmaxf(mx, __shfl_xor(mx, 32));
        const float mn = fmaxf(m_, mx);
        float alpha = 1.f;
        if (__any(mx > m_)) {
            alpha = fexp2(m_ - mn);       // 0 on first tile
#pragma unroll
            for (int mt = 0; mt < 4; ++mt)
#pragma unroll
                for (int r = 0; r < 16; ++r) Ot[mt][r] *= alpha;
        }
        m_ = mn;

        // ---- P = exp2(s-m), pack bf16 pairs; row sum ----
        float s_loc = 0.f;
        unsigned Pp[16];
#pragma unroll
        for (int kt = 0; kt < 2; ++kt)
#pragma unroll
            for (int p = 0; p < 8; ++p) {
                const float p0 = fexp2(St[kt][2 * p] - mn);
                const float p1 = fexp2(St[kt][2 * p + 1] - mn);
                s_loc += p0 + p1;
                Pp[kt * 8 + p] = pack_bf16(p0, p1);
            }
        s_loc += __shfl_xor(s_loc, 32);
        l_ = l_ * alpha + s_loc;

        // ---- Ot += V P^T ----
#pragma unroll
        for (int ks4 = 0; ks4 < 4; ++ks4) {
            const int base = (ks4 >> 1) * 8 + 4 * (ks4 & 1);
            const unsigned pa = Pp[base + 0], pb = Pp[base + 1];
            const unsigned pc = Pp[base + 2], pd = Pp[base + 3];
            const unsigned x0 = (unsigned)__shfl_xor((int)(h2 ? pa : pc), 32);
            const unsigned x1 = (unsigned)__shfl_xor((int)(h2 ? pb : pd), 32);
            union { unsigned u[4]; short8 s8; } fr;
            fr.u[0] = h2 ? x0 : pa;
            fr.u[1] = h2 ? x1 : pb;
            fr.u[2] = h2 ? pc : x0;
            fr.u[3] = h2 ? pd : x1;
#pragma unroll
            for (int mt = 0; mt < 4; ++mt) {
                const short8 a = *(const short8*)(VsA + ks4 * 2048 + mt * 256);
                Ot[mt] = __builtin_amdgcn_mfma_f32_32x32x16_bf16(a, fr.s8, Ot[mt], 0, 0, 0);
            }
        }

        kdma += 64 * 128;
        vdma += 64;
    }

    // ---- epilogue: transpose Ot/l via LDS, coalesced store ----
    __syncthreads();   // both waves done with tiles
    unsigned short* Es = (unsigned short*)Ks2 + w * 4096;   // 32q x 128d per wave
    const float inv = 1.0f / l_;
#pragma unroll
    for (int mt = 0; mt < 4; ++mt)
#pragma unroll
        for (int g = 0; g < 4; ++g) {
            uint2 pk;
            pk.x = pack_bf16(Ot[mt][4 * g + 0] * inv, Ot[mt][4 * g + 1] * inv);
            pk.y = pack_bf16(Ot[mt][4 * g + 2] * inv, Ot[mt][4 * g + 3] * inv);
            const int chunk = (4 * mt + g) ^ (ln & 15);
            *(uint2*)&Es[ln * 128 + chunk * 8 + 4 * h2] = pk;
        }
    __syncthreads();
#pragma unroll
    for (int pp = 0; pp < 8; ++pp) {
        const int f = pp * 64 + lane;
        const int q = f >> 4, c = f & 15;
        const short8 v = *(const short8*)&Es[q * 128 + ((c ^ (q & 15)) * 8)];
        *(short8*)(O + (size_t)(b * 2048 + s0 + 32 * w + q) * 2048 + h * 128 + c * 8) = v;
    }
}

// ---------------------------------------------------------------------------
extern "C" void kernel_launch(void* const* d_in, const int* in_sizes, int n_in,
                              void* d_out, int out_size, void* d_ws, size_t ws_size,
                              hipStream_t stream) {
    const float* hs = (const float*)d_in[0];
    const float* k  = (const float*)d_in[1];
    const float* v  = (const float*)d_in[2];
    const float* wq = (const float*)d_in[3];
    const float* bq = (const float*)d_in[4];
    const float* wp = (const float*)d_in[5];
    const float* bp = (const float*)d_in[6];
    float* out = (float*)d_out;

    unsigned short* hsb  = (unsigned short*)d_ws;     // 8,388,608
    unsigned short* wqb  = hsb  + 8388608;            // 4,194,304
    unsigned short* kb   = wqb  + 4194304;            // 2,097,152
    unsigned short* vtb  = kb   + 2097152;            // 2,097,152
    unsigned short* qbuf = vtb  + 2097152;            // 8,388,608
    unsigned short* abuf = qbuf + 8388608;            // 8,388,608
    unsigned short* wpb  = hsb;                       // alias (hs dead after GEMM1)

    cvt_bf16<<<4096, 256, 0, stream>>>(hs, hsb);
    cvt_bf16<<<2048, 256, 0, stream>>>(wq, wqb);
    cvt_bf16<<<1024, 256, 0, stream>>>(k, kb);
    vtrans_bf16<<<dim3(32, 2, 8), 256, 0, stream>>>(v, vtb);

    dim3 gG(16, 32);
    gemm_nt_mfma<true><<<gG, 256, 0, stream>>>(hsb, wqb, bq, qbuf, 4096, 2048, 2048);
    cvt_bf16<<<2048, 256, 0, stream>>>(wp, wpb);
    attn_mfma4<<<1024, 128, 0, stream>>>(qbuf, kb, vtb, abuf);
    gemm_nt_mfma<false><<<gG, 256, 0, stream>>>(abuf, wpb, bp, out, 4096, 2048, 2048);
}

// Round 6
// 336.260 us; speedup vs baseline: 1.0486x; 1.0486x over previous
//
#include <hip/hip_runtime.h>
#include <math.h>

// B=2, S=2048, H=2048, NH=16, KVH=4, D=128, layer 5.
// GEMMs on mfma_f32_16x16x32_bf16; attention on mfma_f32_32x32x16_bf16.
// Attention softmax in log2 domain; scale log2e/sqrt(128) folded into Q via
// GEMM1 epilogue. masked logit = huge negative (exp2 -> 0, matches ref).

#define RSQ128 0.08838834764831845
#define LOG2E  1.4426950408889634
#define RS2L   ((float)(RSQ128 * LOG2E))
#define MASK2  (-567000.0f)

typedef __attribute__((ext_vector_type(8))) short short8;    // 8 bf16 = 4 VGPR
typedef __attribute__((ext_vector_type(4))) float f32x4;     // 16x16 C/D
typedef __attribute__((ext_vector_type(16))) float f32x16;   // 32x32 C/D

static __device__ __forceinline__ unsigned short f2bf(float x) {
    union { float f; unsigned u; } v; v.f = x;
    unsigned r = v.u + 0x7FFFu + ((v.u >> 16) & 1u);   // RNE
    return (unsigned short)(r >> 16);
}

static __device__ __forceinline__ unsigned pack_bf16(float lo, float hi) {
#if __has_builtin(__builtin_amdgcn_cvt_pk_bf16_f32)
    return __builtin_bit_cast(unsigned, __builtin_amdgcn_cvt_pk_bf16_f32(lo, hi));
#else
    return (unsigned)f2bf(lo) | ((unsigned)f2bf(hi) << 16);
#endif
}

static __device__ __forceinline__ float fexp2(float x) {
#if __has_builtin(__builtin_amdgcn_exp2f)
    return __builtin_amdgcn_exp2f(x);
#else
    return exp2f(x);
#endif
}

static __device__ __forceinline__ void gl_lds16(const void* g, void* l) {
    __builtin_amdgcn_global_load_lds(
        (const __attribute__((address_space(1))) void*)g,
        (__attribute__((address_space(3))) void*)l, 16, 0, 0);
}

// ---------------------------------------------------------------------------
// fp32 -> bf16 convert, 8 elems/thread
// ---------------------------------------------------------------------------
__global__ void cvt_bf16(const float* __restrict__ in, unsigned short* __restrict__ out) {
    const int i = (blockIdx.x * 256 + threadIdx.x) * 8;
    const float4 a = *(const float4*)(in + i);
    const float4 b = *(const float4*)(in + i + 4);
    short8 o;
    o[0] = (short)f2bf(a.x); o[1] = (short)f2bf(a.y);
    o[2] = (short)f2bf(a.z); o[3] = (short)f2bf(a.w);
    o[4] = (short)f2bf(b.x); o[5] = (short)f2bf(b.y);
    o[6] = (short)f2bf(b.z); o[7] = (short)f2bf(b.w);
    *(short8*)(out + i) = o;
}

// ---------------------------------------------------------------------------
// K prepack: fp32 [8][2048][128] -> bf16 [8][64 tiles][16 ch][32 key][8]
// (DMA-native: each 1KB run = one chunk-column of a 32-key tile)
// ---------------------------------------------------------------------------
__global__ void kprep_bf16(const float* __restrict__ K, unsigned short* __restrict__ Kpk) {
    const int t = blockIdx.x, bkh = blockIdx.y, tid = threadIdx.x;
    const float* src = K + ((size_t)bkh * 2048 + t * 32) * 128;
    unsigned short* dst = Kpk + ((size_t)bkh * 64 + t) * 4096;
#pragma unroll
    for (int p = 0; p < 2; ++p) {
        const int g = p * 256 + tid;           // 0..511
        const int ch = g >> 5, key = g & 31;
        const float4 a = *(const float4*)(src + key * 128 + ch * 8);
        const float4 b = *(const float4*)(src + key * 128 + ch * 8 + 4);
        short8 o;
        o[0] = (short)f2bf(a.x); o[1] = (short)f2bf(a.y);
        o[2] = (short)f2bf(a.z); o[3] = (short)f2bf(a.w);
        o[4] = (short)f2bf(b.x); o[5] = (short)f2bf(b.y);
        o[6] = (short)f2bf(b.z); o[7] = (short)f2bf(b.w);
        *(short8*)(dst + ch * 256 + key * 8) = o;
    }
}

// ---------------------------------------------------------------------------
// V prepack: fp32 [8][2048][128] -> bf16 [8][64 tiles][4 kc][128 d][8]
// (transposed per tile: chunk kc holds keys 8kc..8kc+7 for each d)
// ---------------------------------------------------------------------------
__global__ void vprep_bf16(const float* __restrict__ V, unsigned short* __restrict__ Vpk) {
    __shared__ float Ts[32][132];
    const int t = blockIdx.x, bkh = blockIdx.y, tid = threadIdx.x;
    const float* src = V + ((size_t)bkh * 2048 + t * 32) * 128;
    unsigned short* dst = Vpk + ((size_t)bkh * 64 + t) * 4096;
#pragma unroll
    for (int p = 0; p < 4; ++p) {
        const int g = p * 256 + tid;           // 0..1023 float4s
        const int key = g >> 5, cq = g & 31;
        const float4 v = *(const float4*)(src + key * 128 + cq * 4);
        *(float4*)&Ts[key][cq * 4] = v;
    }
    __syncthreads();
#pragma unroll
    for (int p = 0; p < 2; ++p) {
        const int g = p * 256 + tid;           // 0..511
        const int kc = g >> 7, d = g & 127;
        short8 o;
#pragma unroll
        for (int j = 0; j < 8; ++j) o[j] = (short)f2bf(Ts[kc * 8 + j][d]);
        *(short8*)(dst + kc * 1024 + d * 8) = o;
    }
}

// ---------------------------------------------------------------------------
// NT GEMM bf16 MFMA + bias + output scale (known good; oscale folds the
// attention logit scale into Q at GEMM1)
// ---------------------------------------------------------------------------
template <bool BF16OUT>
__global__ __launch_bounds__(256, 2) void gemm_nt_mfma(
    const unsigned short* __restrict__ A,
    const unsigned short* __restrict__ W,
    const float* __restrict__ bias,
    void* __restrict__ Cout, int M, int N, int K, float oscale)
{
    __shared__ __align__(16) unsigned short As[128 * 32];
    __shared__ __align__(16) unsigned short Ws[128 * 32];
    const int tid = threadIdx.x, lane = tid & 63, w = tid >> 6;
    const int wm = w & 1, wn = w >> 1;
    const int m0 = blockIdx.y * 128, n0 = blockIdx.x * 128;
    const int r0 = tid >> 2, c0 = tid & 3;

    const unsigned short* Ag = A + (size_t)(m0 + r0) * K + c0 * 8;
    const unsigned short* Wg = W + (size_t)(n0 + r0) * K + c0 * 8;

    f32x4 acc[4][4];
#pragma unroll
    for (int i = 0; i < 4; ++i)
#pragma unroll
        for (int j = 0; j < 4; ++j) acc[i][j] = (f32x4){0.f, 0.f, 0.f, 0.f};

    const int lm = lane & 15, lk = (lane >> 4) * 8;

    for (int k0 = 0; k0 < K; k0 += 32) {
        __syncthreads();
        gl_lds16(Ag + k0,                  As + tid * 8);
        gl_lds16(Ag + (size_t)64 * K + k0, As + (tid + 256) * 8);
        gl_lds16(Wg + k0,                  Ws + tid * 8);
        gl_lds16(Wg + (size_t)64 * K + k0, Ws + (tid + 256) * 8);
        __syncthreads();

        short8 a[4], b[4];
#pragma unroll
        for (int i = 0; i < 4; ++i)
            a[i] = *(const short8*)&As[(64 * wm + 16 * i + lm) * 32 + lk];
#pragma unroll
        for (int j = 0; j < 4; ++j)
            b[j] = *(const short8*)&Ws[(64 * wn + 16 * j + lm) * 32 + lk];
#pragma unroll
        for (int i = 0; i < 4; ++i)
#pragma unroll
            for (int j = 0; j < 4; ++j)
                acc[i][j] = __builtin_amdgcn_mfma_f32_16x16x32_bf16(a[i], b[j], acc[i][j], 0, 0, 0);
    }

    float bv[4];
#pragma unroll
    for (int j = 0; j < 4; ++j) bv[j] = bias[n0 + 64 * wn + 16 * j + lm];
#pragma unroll
    for (int i = 0; i < 4; ++i)
#pragma unroll
        for (int reg = 0; reg < 4; ++reg) {
            const int row = m0 + 64 * wm + 16 * i + 4 * (lane >> 4) + reg;
#pragma unroll
            for (int j = 0; j < 4; ++j) {
                const int col = n0 + 64 * wn + 16 * j + lm;
                const float v = (acc[i][j][reg] + bv[j]) * oscale;
                if (BF16OUT) ((unsigned short*)Cout)[(size_t)row * N + col] = f2bf(v);
                else         ((float*)Cout)[(size_t)row * N + col] = v;
            }
        }
}

// ---------------------------------------------------------------------------
// Flash attention v5: Bc=32, double-buffered coalesced DMA staging, one
// barrier per iteration (DMA for tile t+1 in flight during compute of t).
// Br=64 (2 waves x 32 q), grid 1024 blocks, 32KB LDS.
//   Ks2[buf][8 x 512]: K tile [ch 0..15][key 0..31][8]  (1KB DMA runs)
//   Vs2[buf][8 x 512]: V tile [kc 0..3][d 0..127][8]
// wave0 DMAs K, wave1 DMAs V. All fragment reads linear, conflict-free.
// St = K*Q^T (col=q); Ot = V*P^T (P via 2 shfl_xor per 16-k step).
// ---------------------------------------------------------------------------
__global__ __launch_bounds__(128, 4) void attn_mfma5(
    const unsigned short* __restrict__ Q,   // [4096][2048] bf16, pre-scaled
    const unsigned short* __restrict__ Kpk, // [8][64][16][32][8] bf16
    const unsigned short* __restrict__ Vpk, // [8][64][4][128][8] bf16
    unsigned short* __restrict__ O)         // [4096][2048] bf16
{
    __shared__ __align__(16) unsigned short Ks2[2 * 4096];   // 16KB
    __shared__ __align__(16) unsigned short Vs2[2 * 4096];   // 16KB

    const int tid = threadIdx.x, lane = tid & 63, w = tid >> 6;  // w in {0,1}
    const int h2 = lane >> 5;
    const int ln = lane & 31;

    // qb permutation: stride-256 block sets have ~constant total work
    const int bid = blockIdx.x;
    const int jj = bid >> 5;
    const int aa = jj & 7, bb = jj >> 3;
    const int qb = 8 * bb + ((bb & 1) ? (7 - aa) : aa);
    const int bh = bid & 31;
    const int s0 = qb * 64;
    const int b = bh >> 4, h = bh & 15, kh = h >> 2;

    const unsigned short* Kbase = Kpk + (size_t)(b * 4 + kh) * 64 * 4096;
    const unsigned short* Vbase = Vpk + (size_t)(b * 4 + kh) * 64 * 4096;

    // ---- hoist Q fragments (pre-scaled by RS2L in GEMM1) ----
    const int qg = s0 + 32 * w + ln;
    const unsigned short* Qp = Q + (size_t)(b * 2048 + qg) * 2048 + h * 128 + h2 * 8;
    short8 Qreg[8];
#pragma unroll
    for (int ks = 0; ks < 8; ++ks) Qreg[ks] = *(const short8*)(Qp + ks * 16);

    f32x16 Ot[4];
#pragma unroll
    for (int mt = 0; mt < 4; ++mt)
#pragma unroll
        for (int r = 0; r < 16; ++r) Ot[mt][r] = 0.f;
    float m_ = -INFINITY, l_ = 0.f;

    // prologue: DMA tile 0 into buffer 0
    if (w == 0) {
#pragma unroll
        for (int i = 0; i < 8; ++i)
            gl_lds16(Kbase + i * 512 + lane * 8, Ks2 + i * 512);
    } else {
#pragma unroll
        for (int i = 0; i < 8; ++i)
            gl_lds16(Vbase + i * 512 + lane * 8, Vs2 + i * 512);
    }
    const unsigned short* kNext = Kbase + 4096 + lane * 8;
    const unsigned short* vNext = Vbase + 4096 + lane * 8;

    int buf = 0;
    const int wq_hi = s0 + 32 * w + 31;       // wave's max q row
    for (int t0 = 0; t0 <= s0 + 32; t0 += 32) {
        __syncthreads();   // drains this tile's DMA; fences prev-buf reads

        if (t0 <= s0) {    // prefetch next tile into other buffer
            unsigned short* ob = (buf ? (unsigned short*)0 : (unsigned short*)0);
            (void)ob;
            if (w == 0) {
                unsigned short* dst = Ks2 + (buf ^ 1) * 4096;
#pragma unroll
                for (int i = 0; i < 8; ++i) gl_lds16(kNext + i * 512, dst + i * 512);
            } else {
                unsigned short* dst = Vs2 + (buf ^ 1) * 4096;
#pragma unroll
                for (int i = 0; i < 8; ++i) gl_lds16(vNext + i * 512, dst + i * 512);
            }
            kNext += 4096; vNext += 4096;
        }

        if (t0 <= wq_hi) {
            const unsigned short* KsA = Ks2 + buf * 4096 + h2 * 256 + ln * 8;
            const unsigned short* VsA = Vs2 + buf * 4096 + h2 * 1024 + ln * 8;

            // ---- St = K Q^T : col=q=ln, rows=key(0..31) ----
            f32x16 St;
#pragma unroll
            for (int r = 0; r < 16; ++r) St[r] = 0.f;
#pragma unroll
            for (int ks = 0; ks < 8; ++ks) {
                const short8 a = *(const short8*)(KsA + ks * 512);
                St = __builtin_amdgcn_mfma_f32_32x32x16_bf16(a, Qreg[ks], St, 0, 0, 0);
            }

            // ---- mask (scale pre-folded); row max ----
            float mx = -INFINITY;
            if (t0 + 31 <= s0 + 32 * w) {     // wave fully unmasked
#pragma unroll
                for (int r = 0; r < 16; ++r) mx = fmaxf(mx, St[r]);
            } else {
#pragma unroll
                for (int r = 0; r < 16; ++r) {
                    const int key = t0 + (r & 3) + 8 * (r >> 2) + 4 * h2;
                    const float v = (key <= qg) ? St[r] : MASK2;
                    St[r] = v;
                    mx = fmaxf(mx, v);
                }
            }
            mx = fmaxf(mx, __shfl_xor(mx, 32));
            const float mn = fmaxf(m_, mx);
            float alpha = 1.f;
            if (__any(mx > m_)) {
                alpha = fexp2(m_ - mn);       // 0 on first tile
#pragma unroll
                for (int mt = 0; mt < 4; ++mt)
#pragma unroll
                    for (int r = 0; r < 16; ++r) Ot[mt][r] *= alpha;
            }
            m_ = mn;

            // ---- P = exp2(s-m), packed; row sum ----
            float s_loc = 0.f;
            unsigned Pp[8];
#pragma unroll
            for (int p = 0; p < 8; ++p) {
                const float p0 = fexp2(St[2 * p] - mn);
                const float p1 = fexp2(St[2 * p + 1] - mn);
                s_loc += p0 + p1;
                Pp[p] = pack_bf16(p0, p1);
            }
            s_loc += __shfl_xor(s_loc, 32);
            l_ = l_ * alpha + s_loc;

            // ---- Ot += V P^T (2 k-steps of 16 keys) ----
#pragma unroll
            for (int ks4 = 0; ks4 < 2; ++ks4) {
                const unsigned pa = Pp[4 * ks4 + 0], pb = Pp[4 * ks4 + 1];
                const unsigned pc = Pp[4 * ks4 + 2], pd = Pp[4 * ks4 + 3];
                const unsigned x0 = (unsigned)__shfl_xor((int)(h2 ? pa : pc), 32);
                const unsigned x1 = (unsigned)__shfl_xor((int)(h2 ? pb : pd), 32);
                union { unsigned u[4]; short8 s8; } fr;
                fr.u[0] = h2 ? x0 : pa;
                fr.u[1] = h2 ? x1 : pb;
                fr.u[2] = h2 ? pc : x0;
                fr.u[3] = h2 ? pd : x1;
#pragma unroll
                for (int mt = 0; mt < 4; ++mt) {
                    const short8 a = *(const short8*)(VsA + ks4 * 2048 + mt * 256);
                    Ot[mt] = __builtin_amdgcn_mfma_f32_32x32x16_bf16(a, fr.s8, Ot[mt], 0, 0, 0);
                }
            }
        }
        buf ^= 1;
    }

    // ---- epilogue: transpose Ot/l via LDS, coalesced store ----
    __syncthreads();
    unsigned short* Es = Ks2 + w * 4096;   // 32q x 128d per wave
    const float inv = 1.0f / l_;
#pragma unroll
    for (int mt = 0; mt < 4; ++mt)
#pragma unroll
        for (int g = 0; g < 4; ++g) {
            uint2 pk;
            pk.x = pack_bf16(Ot[mt][4 * g + 0] * inv, Ot[mt][4 * g + 1] * inv);
            pk.y = pack_bf16(Ot[mt][4 * g + 2] * inv, Ot[mt][4 * g + 3] * inv);
            const int chunk = (4 * mt + g) ^ (ln & 15);
            *(uint2*)&Es[ln * 128 + chunk * 8 + 4 * h2] = pk;
        }
    __syncthreads();
#pragma unroll
    for (int pp = 0; pp < 8; ++pp) {
        const int f = pp * 64 + lane;
        const int q = f >> 4, c = f & 15;
        const short8 v = *(const short8*)&Es[q * 128 + ((c ^ (q & 15)) * 8)];
        *(short8*)(O + (size_t)(b * 2048 + s0 + 32 * w + q) * 2048 + h * 128 + c * 8) = v;
    }
}

// ---------------------------------------------------------------------------
extern "C" void kernel_launch(void* const* d_in, const int* in_sizes, int n_in,
                              void* d_out, int out_size, void* d_ws, size_t ws_size,
                              hipStream_t stream) {
    const float* hs = (const float*)d_in[0];
    const float* k  = (const float*)d_in[1];
    const float* v  = (const float*)d_in[2];
    const float* wq = (const float*)d_in[3];
    const float* bq = (const float*)d_in[4];
    const float* wp = (const float*)d_in[5];
    const float* bp = (const float*)d_in[6];
    float* out = (float*)d_out;

    unsigned short* hsb  = (unsigned short*)d_ws;     // 8,388,608
    unsigned short* wqb  = hsb  + 8388608;            // 4,194,304
    unsigned short* kpk  = wqb  + 4194304;            // 2,097,152
    unsigned short* vpk  = kpk  + 2097152;            // 2,097,152
    unsigned short* qbuf = vpk  + 2097152;            // 8,388,608
    unsigned short* abuf = qbuf + 8388608;            // 8,388,608
    unsigned short* wpb  = hsb;                       // alias (hs dead after GEMM1)

    cvt_bf16<<<4096, 256, 0, stream>>>(hs, hsb);
    cvt_bf16<<<2048, 256, 0, stream>>>(wq, wqb);
    kprep_bf16<<<dim3(64, 8), 256, 0, stream>>>(k, kpk);
    vprep_bf16<<<dim3(64, 8), 256, 0, stream>>>(v, vpk);

    dim3 gG(16, 32);
    gemm_nt_mfma<true><<<gG, 256, 0, stream>>>(hsb, wqb, bq, qbuf, 4096, 2048, 2048, RS2L);
    cvt_bf16<<<2048, 256, 0, stream>>>(wp, wpb);
    attn_mfma5<<<1024, 128, 0, stream>>>(qbuf, kpk, vpk, abuf);
    gemm_nt_mfma<false><<<gG, 256, 0, stream>>>(abuf, wpb, bp, out, 4096, 2048, 2048, 1.0f);
}

// Round 7
// 313.401 us; speedup vs baseline: 1.1251x; 1.0729x over previous
//
#include <hip/hip_runtime.h>
#include <math.h>

// B=2, S=2048, H=2048, NH=16, KVH=4, D=128, layer 5.
// GEMMs on mfma_f32_16x16x32_bf16 (double-buffered LDS staging);
// attention on mfma_f32_32x32x16_bf16 with 2-way key-split waves.
// Softmax in log2 domain; scale log2e/sqrt(128) folded into Q via GEMM1.

#define RSQ128 0.08838834764831845
#define LOG2E  1.4426950408889634
#define RS2L   ((float)(RSQ128 * LOG2E))
#define MASK2  (-567000.0f)

typedef __attribute__((ext_vector_type(8))) short short8;    // 8 bf16 = 4 VGPR
typedef __attribute__((ext_vector_type(4))) float f32x4;     // 16x16 C/D
typedef __attribute__((ext_vector_type(16))) float f32x16;   // 32x32 C/D

static __device__ __forceinline__ unsigned short f2bf(float x) {
    union { float f; unsigned u; } v; v.f = x;
    unsigned r = v.u + 0x7FFFu + ((v.u >> 16) & 1u);   // RNE
    return (unsigned short)(r >> 16);
}

static __device__ __forceinline__ unsigned pack_bf16(float lo, float hi) {
#if __has_builtin(__builtin_amdgcn_cvt_pk_bf16_f32)
    return __builtin_bit_cast(unsigned, __builtin_amdgcn_cvt_pk_bf16_f32(lo, hi));
#else
    return (unsigned)f2bf(lo) | ((unsigned)f2bf(hi) << 16);
#endif
}

static __device__ __forceinline__ float fexp2(float x) {
#if __has_builtin(__builtin_amdgcn_exp2f)
    return __builtin_amdgcn_exp2f(x);
#else
    return exp2f(x);
#endif
}

static __device__ __forceinline__ void gl_lds16(const void* g, void* l) {
    __builtin_amdgcn_global_load_lds(
        (const __attribute__((address_space(1))) void*)g,
        (__attribute__((address_space(3))) void*)l, 16, 0, 0);
}

// ---------------------------------------------------------------------------
// fp32 -> bf16 convert, 8 elems/thread
// ---------------------------------------------------------------------------
__global__ void cvt_bf16(const float* __restrict__ in, unsigned short* __restrict__ out) {
    const int i = (blockIdx.x * 256 + threadIdx.x) * 8;
    const float4 a = *(const float4*)(in + i);
    const float4 b = *(const float4*)(in + i + 4);
    short8 o;
    o[0] = (short)f2bf(a.x); o[1] = (short)f2bf(a.y);
    o[2] = (short)f2bf(a.z); o[3] = (short)f2bf(a.w);
    o[4] = (short)f2bf(b.x); o[5] = (short)f2bf(b.y);
    o[6] = (short)f2bf(b.z); o[7] = (short)f2bf(b.w);
    *(short8*)(out + i) = o;
}

// ---------------------------------------------------------------------------
// K prepack: fp32 [8][2048][128] -> bf16 [8][64 tiles][16 ch][32 key][8]
// ---------------------------------------------------------------------------
__global__ void kprep_bf16(const float* __restrict__ K, unsigned short* __restrict__ Kpk) {
    const int t = blockIdx.x, bkh = blockIdx.y, tid = threadIdx.x;
    const float* src = K + ((size_t)bkh * 2048 + t * 32) * 128;
    unsigned short* dst = Kpk + ((size_t)bkh * 64 + t) * 4096;
#pragma unroll
    for (int p = 0; p < 2; ++p) {
        const int g = p * 256 + tid;
        const int ch = g >> 5, key = g & 31;
        const float4 a = *(const float4*)(src + key * 128 + ch * 8);
        const float4 b = *(const float4*)(src + key * 128 + ch * 8 + 4);
        short8 o;
        o[0] = (short)f2bf(a.x); o[1] = (short)f2bf(a.y);
        o[2] = (short)f2bf(a.z); o[3] = (short)f2bf(a.w);
        o[4] = (short)f2bf(b.x); o[5] = (short)f2bf(b.y);
        o[6] = (short)f2bf(b.z); o[7] = (short)f2bf(b.w);
        *(short8*)(dst + ch * 256 + key * 8) = o;
    }
}

// ---------------------------------------------------------------------------
// V prepack: fp32 [8][2048][128] -> bf16 [8][64 tiles][4 kc][128 d][8]
// ---------------------------------------------------------------------------
__global__ void vprep_bf16(const float* __restrict__ V, unsigned short* __restrict__ Vpk) {
    __shared__ float Ts[32][132];
    const int t = blockIdx.x, bkh = blockIdx.y, tid = threadIdx.x;
    const float* src = V + ((size_t)bkh * 2048 + t * 32) * 128;
    unsigned short* dst = Vpk + ((size_t)bkh * 64 + t) * 4096;
#pragma unroll
    for (int p = 0; p < 4; ++p) {
        const int g = p * 256 + tid;
        const int key = g >> 5, cq = g & 31;
        const float4 v = *(const float4*)(src + key * 128 + cq * 4);
        *(float4*)&Ts[key][cq * 4] = v;
    }
    __syncthreads();
#pragma unroll
    for (int p = 0; p < 2; ++p) {
        const int g = p * 256 + tid;
        const int kc = g >> 7, d = g & 127;
        short8 o;
#pragma unroll
        for (int j = 0; j < 8; ++j) o[j] = (short)f2bf(Ts[kc * 8 + j][d]);
        *(short8*)(dst + kc * 1024 + d * 8) = o;
    }
}

// ---------------------------------------------------------------------------
// NT GEMM bf16 MFMA, double-buffered DMA staging (one barrier per K-iter).
// ---------------------------------------------------------------------------
template <bool BF16OUT>
__global__ __launch_bounds__(256, 2) void gemm_nt_mfma(
    const unsigned short* __restrict__ A,
    const unsigned short* __restrict__ W,
    const float* __restrict__ bias,
    void* __restrict__ Cout, int M, int N, int K, float oscale)
{
    __shared__ __align__(16) unsigned short As[2][4096];
    __shared__ __align__(16) unsigned short Ws[2][4096];
    const int tid = threadIdx.x, lane = tid & 63, w = tid >> 6;
    const int wm = w & 1, wn = w >> 1;
    const int m0 = blockIdx.y * 128, n0 = blockIdx.x * 128;
    const int r0 = tid >> 2, c0 = tid & 3;

    const unsigned short* Ag = A + (size_t)(m0 + r0) * K + c0 * 8;
    const unsigned short* Wg = W + (size_t)(n0 + r0) * K + c0 * 8;

    f32x4 acc[4][4];
#pragma unroll
    for (int i = 0; i < 4; ++i)
#pragma unroll
        for (int j = 0; j < 4; ++j) acc[i][j] = (f32x4){0.f, 0.f, 0.f, 0.f};

    const int lm = lane & 15, lk = (lane >> 4) * 8;

    // prologue: DMA k0=0 into buffer 0
    gl_lds16(Ag,                  As[0] + tid * 8);
    gl_lds16(Ag + (size_t)64 * K, As[0] + (tid + 256) * 8);
    gl_lds16(Wg,                  Ws[0] + tid * 8);
    gl_lds16(Wg + (size_t)64 * K, Ws[0] + (tid + 256) * 8);

    int buf = 0;
    for (int k0 = 0; k0 < K; k0 += 32) {
        __syncthreads();              // drains current buffer's DMA
        const int kn = k0 + 32;
        if (kn < K) {                 // prefetch next tile into other buffer
            unsigned short* Ad = As[buf ^ 1];
            unsigned short* Wd = Ws[buf ^ 1];
            gl_lds16(Ag + kn,                  Ad + tid * 8);
            gl_lds16(Ag + (size_t)64 * K + kn, Ad + (tid + 256) * 8);
            gl_lds16(Wg + kn,                  Wd + tid * 8);
            gl_lds16(Wg + (size_t)64 * K + kn, Wd + (tid + 256) * 8);
        }

        short8 a[4], b[4];
#pragma unroll
        for (int i = 0; i < 4; ++i)
            a[i] = *(const short8*)&As[buf][(64 * wm + 16 * i + lm) * 32 + lk];
#pragma unroll
        for (int j = 0; j < 4; ++j)
            b[j] = *(const short8*)&Ws[buf][(64 * wn + 16 * j + lm) * 32 + lk];
#pragma unroll
        for (int i = 0; i < 4; ++i)
#pragma unroll
            for (int j = 0; j < 4; ++j)
                acc[i][j] = __builtin_amdgcn_mfma_f32_16x16x32_bf16(a[i], b[j], acc[i][j], 0, 0, 0);
        buf ^= 1;
    }

    float bv[4];
#pragma unroll
    for (int j = 0; j < 4; ++j) bv[j] = bias[n0 + 64 * wn + 16 * j + lm];
#pragma unroll
    for (int i = 0; i < 4; ++i)
#pragma unroll
        for (int reg = 0; reg < 4; ++reg) {
            const int row = m0 + 64 * wm + 16 * i + 4 * (lane >> 4) + reg;
#pragma unroll
            for (int j = 0; j < 4; ++j) {
                const int col = n0 + 64 * wn + 16 * j + lm;
                const float v = (acc[i][j][reg] + bv[j]) * oscale;
                if (BF16OUT) ((unsigned short*)Cout)[(size_t)row * N + col] = f2bf(v);
                else         ((float*)Cout)[(size_t)row * N + col] = v;
            }
        }
}

// ---------------------------------------------------------------------------
// Flash attention v6: 4 waves = (q-half x key-parity). Br=64, Bc=32/wave.
// Each wave owns private (m,l,O) over its key parity (even/odd 32-key tiles;
// tile count per block is 2qb+2 = always even); states merged via LDS at end.
// LDS: Ks[2]/Vs[2] tile pair (32KB) + m/l arrays (1KB) -> 4 blocks/CU,
// 16 waves/CU (2x R6 TLP). Staging: each wave DMAs one 8KB tile of the pair.
// ---------------------------------------------------------------------------
__global__ __launch_bounds__(256, 4) void attn_mfma6(
    const unsigned short* __restrict__ Q,   // [4096][2048] bf16, pre-scaled
    const unsigned short* __restrict__ Kpk, // [8][64][16][32][8] bf16
    const unsigned short* __restrict__ Vpk, // [8][64][4][128][8] bf16
    unsigned short* __restrict__ O)         // [4096][2048] bf16
{
    __shared__ __align__(16) unsigned short Ks[2][4096];   // 16KB (pair of K tiles)
    __shared__ __align__(16) unsigned short Vs[2][4096];   // 16KB (pair of V tiles)
    __shared__ float Msm[2][64], Lsm[2][64];

    const int tid = threadIdx.x, lane = tid & 63, w = tid >> 6;  // w 0..3
    const int qhalf = w & 1, pz = w >> 1;
    const int h2 = lane >> 5, ln = lane & 31;

    // qb permutation: stride-256 co-resident sets have constant total work
    const int bid = blockIdx.x;
    const int jj = bid >> 5;
    const int aa = jj & 7, bb = jj >> 3;
    const int qb = 8 * bb + ((bb & 1) ? (7 - aa) : aa);
    const int bh = bid & 31;
    const int s0 = qb * 64;
    const int b = bh >> 4, h = bh & 15, kh = h >> 2;

    const unsigned short* Kbase = Kpk + (size_t)(b * 4 + kh) * 64 * 4096;
    const unsigned short* Vbase = Vpk + (size_t)(b * 4 + kh) * 64 * 4096;

    // staging assignment: w0->K even, w1->K odd, w2->V even, w3->V odd
    const unsigned short* stsrc = (pz == 0 ? Kbase : Vbase) + (size_t)qhalf * 4096 + lane * 8;
    unsigned short* stdst = (pz == 0 ? Ks[qhalf] : Vs[qhalf]);

    // ---- hoist Q fragments (pre-scaled by RS2L in GEMM1) ----
    const int qg = s0 + 32 * qhalf + ln;
    const unsigned short* Qp = Q + (size_t)(b * 2048 + qg) * 2048 + h * 128 + h2 * 8;
    short8 Qreg[8];
#pragma unroll
    for (int ks = 0; ks < 8; ++ks) Qreg[ks] = *(const short8*)(Qp + ks * 16);

    f32x16 Ot[4];
#pragma unroll
    for (int mt = 0; mt < 4; ++mt)
#pragma unroll
        for (int r = 0; r < 16; ++r) Ot[mt][r] = 0.f;
    float m_ = -INFINITY, l_ = 0.f;

    const int wq_hi = s0 + 32 * qhalf + 31;
    const int myofs = 32 * pz;

    for (int j = 0; j <= qb; ++j) {
        __syncthreads();   // prev pair's LDS reads done
        {
            const unsigned short* sp = stsrc + (size_t)j * 8192;
#pragma unroll
            for (int i = 0; i < 8; ++i)
                gl_lds16(sp + i * 512, stdst + i * 512);
        }
        __syncthreads();   // barrier drains DMA

        const int t0 = 64 * j + myofs;
        if (t0 <= wq_hi) {
            const unsigned short* KsA = Ks[pz] + h2 * 256 + ln * 8;
            const unsigned short* VsA = Vs[pz] + h2 * 1024 + ln * 8;

            // ---- St = K Q^T : col=q=ln, rows=key(0..31) ----
            f32x16 St;
#pragma unroll
            for (int r = 0; r < 16; ++r) St[r] = 0.f;
#pragma unroll
            for (int ks = 0; ks < 8; ++ks) {
                const short8 a = *(const short8*)(KsA + ks * 512);
                St = __builtin_amdgcn_mfma_f32_32x32x16_bf16(a, Qreg[ks], St, 0, 0, 0);
            }

            // ---- mask (scale pre-folded); row max ----
            float mx = -INFINITY;
            if (t0 + 31 <= s0 + 32 * qhalf) {   // wave fully unmasked
#pragma unroll
                for (int r = 0; r < 16; ++r) mx = fmaxf(mx, St[r]);
            } else {
#pragma unroll
                for (int r = 0; r < 16; ++r) {
                    const int key = t0 + (r & 3) + 8 * (r >> 2) + 4 * h2;
                    const float v = (key <= qg) ? St[r] : MASK2;
                    St[r] = v;
                    mx = fmaxf(mx, v);
                }
            }
            mx = fmaxf(mx, __shfl_xor(mx, 32));
            const float mn = fmaxf(m_, mx);
            float alpha = 1.f;
            if (__any(mx > m_)) {
                alpha = fexp2(m_ - mn);         // 0 on first tile
#pragma unroll
                for (int mt = 0; mt < 4; ++mt)
#pragma unroll
                    for (int r = 0; r < 16; ++r) Ot[mt][r] *= alpha;
            }
            m_ = mn;

            // ---- P = exp2(s-m), packed; row sum ----
            float s_loc = 0.f;
            unsigned Pp[8];
#pragma unroll
            for (int p = 0; p < 8; ++p) {
                const float p0 = fexp2(St[2 * p] - mn);
                const float p1 = fexp2(St[2 * p + 1] - mn);
                s_loc += p0 + p1;
                Pp[p] = pack_bf16(p0, p1);
            }
            s_loc += __shfl_xor(s_loc, 32);
            l_ = l_ * alpha + s_loc;

            // ---- Ot += V P^T (2 k-steps of 16 keys) ----
#pragma unroll
            for (int ks4 = 0; ks4 < 2; ++ks4) {
                const unsigned pa = Pp[4 * ks4 + 0], pb = Pp[4 * ks4 + 1];
                const unsigned pc = Pp[4 * ks4 + 2], pd = Pp[4 * ks4 + 3];
                const unsigned x0 = (unsigned)__shfl_xor((int)(h2 ? pa : pc), 32);
                const unsigned x1 = (unsigned)__shfl_xor((int)(h2 ? pb : pd), 32);
                union { unsigned u[4]; short8 s8; } fr;
                fr.u[0] = h2 ? x0 : pa;
                fr.u[1] = h2 ? x1 : pb;
                fr.u[2] = h2 ? pc : x0;
                fr.u[3] = h2 ? pd : x1;
#pragma unroll
                for (int mt = 0; mt < 4; ++mt) {
                    const short8 a = *(const short8*)(VsA + ks4 * 2048 + mt * 256);
                    Ot[mt] = __builtin_amdgcn_mfma_f32_32x32x16_bf16(a, fr.s8, Ot[mt], 0, 0, 0);
                }
            }
        }
    }

    // ---- merge key-parity states: parity1 -> LDS (fp32, swizzled), parity0 reads ----
    __syncthreads();
    if (pz == 1) {
        float* dst = qhalf ? (float*)Vs : (float*)Ks;   // 16KB region each
#pragma unroll
        for (int mt = 0; mt < 4; ++mt)
#pragma unroll
            for (int g = 0; g < 4; ++g) {
                float4 v4;
                v4.x = Ot[mt][4 * g + 0]; v4.y = Ot[mt][4 * g + 1];
                v4.z = Ot[mt][4 * g + 2]; v4.w = Ot[mt][4 * g + 3];
                *(float4*)&dst[lane * 64 + (((mt * 4 + g + lane) & 15) * 4)] = v4;
            }
        Msm[qhalf][lane] = m_;
        Lsm[qhalf][lane] = l_;
    }
    __syncthreads();
    if (pz == 0) {
        const float m1 = Msm[qhalf][lane];
        const float l1 = Lsm[qhalf][lane];
        const float* src = qhalf ? (const float*)Vs : (const float*)Ks;
        const float mM = fmaxf(m_, m1);
        const float a0 = fexp2(m_ - mM);
        const float a1 = fexp2(m1 - mM);
        l_ = l_ * a0 + l1 * a1;
#pragma unroll
        for (int mt = 0; mt < 4; ++mt)
#pragma unroll
            for (int g = 0; g < 4; ++g) {
                const float4 v4 = *(const float4*)&src[lane * 64 + (((mt * 4 + g + lane) & 15) * 4)];
                Ot[mt][4 * g + 0] = Ot[mt][4 * g + 0] * a0 + v4.x * a1;
                Ot[mt][4 * g + 1] = Ot[mt][4 * g + 1] * a0 + v4.y * a1;
                Ot[mt][4 * g + 2] = Ot[mt][4 * g + 2] * a0 + v4.z * a1;
                Ot[mt][4 * g + 3] = Ot[mt][4 * g + 3] * a0 + v4.w * a1;
            }
    }
    __syncthreads();   // LDS free for transpose regions

    // ---- epilogue (parity0 waves): normalize, transpose via LDS, store ----
    if (pz == 0) {
        unsigned short* Es = (unsigned short*)Ks + qhalf * 4096;   // 8KB each
        const float inv = 1.0f / l_;
#pragma unroll
        for (int mt = 0; mt < 4; ++mt)
#pragma unroll
            for (int g = 0; g < 4; ++g) {
                uint2 pk;
                pk.x = pack_bf16(Ot[mt][4 * g + 0] * inv, Ot[mt][4 * g + 1] * inv);
                pk.y = pack_bf16(Ot[mt][4 * g + 2] * inv, Ot[mt][4 * g + 3] * inv);
                const int chunk = (4 * mt + g) ^ (ln & 15);
                *(uint2*)&Es[ln * 128 + chunk * 8 + 4 * h2] = pk;
            }
    }
    __syncthreads();
    if (pz == 0) {
        unsigned short* Es = (unsigned short*)Ks + qhalf * 4096;
#pragma unroll
        for (int pp = 0; pp < 8; ++pp) {
            const int f = pp * 64 + lane;
            const int q = f >> 4, c = f & 15;
            const short8 v = *(const short8*)&Es[q * 128 + ((c ^ (q & 15)) * 8)];
            *(short8*)(O + (size_t)(b * 2048 + s0 + 32 * qhalf + q) * 2048 + h * 128 + c * 8) = v;
        }
    }
}

// ---------------------------------------------------------------------------
extern "C" void kernel_launch(void* const* d_in, const int* in_sizes, int n_in,
                              void* d_out, int out_size, void* d_ws, size_t ws_size,
                              hipStream_t stream) {
    const float* hs = (const float*)d_in[0];
    const float* k  = (const float*)d_in[1];
    const float* v  = (const float*)d_in[2];
    const float* wq = (const float*)d_in[3];
    const float* bq = (const float*)d_in[4];
    const float* wp = (const float*)d_in[5];
    const float* bp = (const float*)d_in[6];
    float* out = (float*)d_out;

    unsigned short* hsb  = (unsigned short*)d_ws;     // 8,388,608
    unsigned short* wqb  = hsb  + 8388608;            // 4,194,304
    unsigned short* kpk  = wqb  + 4194304;            // 2,097,152
    unsigned short* vpk  = kpk  + 2097152;            // 2,097,152
    unsigned short* qbuf = vpk  + 2097152;            // 8,388,608
    unsigned short* abuf = qbuf + 8388608;            // 8,388,608
    unsigned short* wpb  = hsb;                       // alias (hs dead after GEMM1)

    cvt_bf16<<<4096, 256, 0, stream>>>(hs, hsb);
    cvt_bf16<<<2048, 256, 0, stream>>>(wq, wqb);
    kprep_bf16<<<dim3(64, 8), 256, 0, stream>>>(k, kpk);
    vprep_bf16<<<dim3(64, 8), 256, 0, stream>>>(v, vpk);

    dim3 gG(16, 32);
    gemm_nt_mfma<true><<<gG, 256, 0, stream>>>(hsb, wqb, bq, qbuf, 4096, 2048, 2048, RS2L);
    cvt_bf16<<<2048, 256, 0, stream>>>(wp, wpb);
    attn_mfma6<<<1024, 256, 0, stream>>>(qbuf, kpk, vpk, abuf);
    gemm_nt_mfma<false><<<gG, 256, 0, stream>>>(abuf, wpb, bp, out, 4096, 2048, 2048, 1.0f);
}